// Round 2
// baseline (459.457 us; speedup 1.0000x reference)
//
#include <hip/hip_runtime.h>

// reset_layer: Out = R^T · X_grid · L^T + X per pixel-group, x (16,2000,2000)
// fp32, bs=10. v4: persistent line-pipelined blocks.
//
// 512 blocks x 512 threads; block grid-strides over (b,h) "row lines"
// (g = blockIdx, +512 each iter; 6-7 lines/block). Per iteration:
//   1. issue NEXT line's 10 float4 loads into xn[] (stay in flight across
//      the barriers -- raw s_barrier + lgkmcnt(0) only, NO vmcnt drain)
//   2. phase A: W-mix of current xc[] in regs -> Ysh (10 ds_write_b128)
//   3. barrier
//   4. phase B: xc[jw] += sum_ihp r[ihp]*Ysh[ihp][jw][wo4]  (identity is
//      already resident in xc -> store = mix + identity), then store.
//   5. barrier (protect Ysh), xc <- xn, next line.
// Stores of line l overlap loads of line l+1 -> continuous HBM pressure;
// the vmcnt wait for xn lands at the register copy, ~2-3k cycles after
// issue, fully hidden under A+B+C.
//
// VGPR budget: xc 40 + xn 40 + r 10 + temps ~ 110 < 128 cap from
// __launch_bounds__(512,4) -> 2 blocks/CU (LDS 80 KB also allows 2).

#define IMG    2000
#define BSZ    10
#define TC     200                 // chunk size = 2000/10
#define CHW    (IMG * IMG)         // 4,000,000
#define NW4    (TC / 4)            // 50 float4 slots per chunk-row slice
#define NLINES (16 * TC)           // 3200 (b,h) lines
#define GRID   512

// Barrier that does NOT drain vmcnt: LDS is the only cross-thread data,
// so lgkmcnt(0) suffices; prefetch loads stay in flight (AITER pattern).
// "memory" clobbers on both sides fence IR-level LDS reordering.
#define BAR() do { asm volatile("s_waitcnt lgkmcnt(0)" ::: "memory"); \
                   __builtin_amdgcn_s_barrier();                      \
                   asm volatile("" ::: "memory"); } while (0)

__global__ __launch_bounds__(512, 4)
void reset_pipe(const float* __restrict__ x,
                const float* __restrict__ leftm,
                const float* __restrict__ rightm,
                float* __restrict__ out)
{
    // Y[ih][jw][wo4] : 10*10*50 float4 = 80,000 B
    __shared__ __align__(16) float4 Ysh[BSZ * BSZ * NW4];

    const int  t      = threadIdx.x;
    const int  ih     = t / NW4;       // 0..9 (10 for the 12 idle threads)
    const int  wo4    = t - ih * NW4;  // 0..49
    const bool active = (t < BSZ * NW4);
    const int  jh     = active ? ih : 0;   // output row == input row

    // R^T row for this thread's output row: r[ihp] = R[ihp][jh].
    // 10 tiny vector loads, once per block, L1/L2-resident.
    float r[BSZ];
    #pragma unroll
    for (int ihp = 0; ihp < BSZ; ++ihp)
        r[ihp] = rightm[ihp * BSZ + jh];

    float4 xc[BSZ], xn[BSZ];
    int g = blockIdx.x;                // current line id in [0, 3200)

    // prologue: load line g
    if (active) {
        const int b = g / TC, h = g - b * TC;
        const float4* rowp =
            (const float4*)(x + (size_t)b * CHW + (size_t)(ih * TC + h) * IMG);
        #pragma unroll
        for (int iw = 0; iw < BSZ; ++iw)
            xc[iw] = rowp[iw * NW4 + wo4];
    }

    while (true) {
        const int gn = g + GRID;

        // ---- issue next line's loads FIRST: deepest possible prefetch
        if (gn < NLINES && active) {
            const int bn = gn / TC, hn = gn - bn * TC;
            const float4* rowp =
                (const float4*)(x + (size_t)bn * CHW + (size_t)(ih * TC + hn) * IMG);
            #pragma unroll
            for (int iw = 0; iw < BSZ; ++iw)
                xn[iw] = rowp[iw * NW4 + wo4];
        }

        // ---- phase A: Y[ih][jw][wo4] = sum_iw L[jw][iw] * xc[iw]
        if (active) {
            #pragma unroll
            for (int jw = 0; jw < BSZ; ++jw) {
                const float l0 = leftm[jw * BSZ + 0];
                float4 y;
                y.x = l0 * xc[0].x; y.y = l0 * xc[0].y;
                y.z = l0 * xc[0].z; y.w = l0 * xc[0].w;
                #pragma unroll
                for (int iw = 1; iw < BSZ; ++iw) {
                    const float l = leftm[jw * BSZ + iw];
                    y.x += l * xc[iw].x; y.y += l * xc[iw].y;
                    y.z += l * xc[iw].z; y.w += l * xc[iw].w;
                }
                Ysh[(ih * BSZ + jw) * NW4 + wo4] = y;
            }
        }

        BAR();   // lgkmcnt(0) only -- xn loads stay in flight

        // ---- phase B: xc[jw] += sum_ihp r[ihp] * Y[ihp][jw][wo4]
        // (xc holds the identity term; becomes the final output)
        if (active) {
            #pragma unroll
            for (int ihp = 0; ihp < BSZ; ++ihp) {
                const float rr = r[ihp];
                #pragma unroll
                for (int jw = 0; jw < BSZ; ++jw) {
                    const float4 y = Ysh[(ihp * BSZ + jw) * NW4 + wo4];
                    xc[jw].x += rr * y.x; xc[jw].y += rr * y.y;
                    xc[jw].z += rr * y.z; xc[jw].w += rr * y.w;
                }
            }
            // ---- store: contiguous ~1024B per wave-instruction
            const int b = g / TC, h = g - b * TC;
            float4* orow =
                (float4*)(out + (size_t)b * CHW + (size_t)(jh * TC + h) * IMG);
            #pragma unroll
            for (int jw = 0; jw < BSZ; ++jw)
                orow[jw * NW4 + wo4] = xc[jw];
        }

        if (gn >= NLINES) break;

        BAR();   // Ysh reads done before next phase-A overwrites

        // advance: vmcnt wait for xn lands here, ~A+B+C cycles after issue
        #pragma unroll
        for (int i = 0; i < BSZ; ++i) xc[i] = xn[i];
        g = gn;
    }
}

extern "C" void kernel_launch(void* const* d_in, const int* in_sizes, int n_in,
                              void* d_out, int out_size, void* d_ws, size_t ws_size,
                              hipStream_t stream) {
    const float* x = (const float*)d_in[0];
    const float* L = (const float*)d_in[1];
    const float* R = (const float*)d_in[2];
    float* out = (float*)d_out;
    // 512 persistent-ish blocks (2/CU), each handles 6-7 of the 3200 lines
    reset_pipe<<<GRID, 512, 0, stream>>>(x, L, R, out);
}

// Round 3
// 455.704 us; speedup vs baseline: 1.0082x; 1.0082x over previous
//
#include <hip/hip_runtime.h>

// reset_layer: Out = R^T · X_grid · L^T + X per pixel-group, x (16,2000,2000)
// fp32, bs=10. v5: half-line blocks for 4 independent barrier domains/CU.
//
// Post-mortem v4: register double-buffer prefetch collapsed (VGPR=64 vs ~100
// needed -> spills, +108MB scratch writes, 3.7 TB/s). Reverted.
//
// v5 = proven v2 two-phase structure, halved along the pixel-column axis:
//   block = one (b, h, half): the 10 rows {ih*200+h}, columns
//   [iw*200 + half*100, +100) for all iw. 256 threads (250 active),
//   LDS 40,000 B -> 4 blocks/CU (vs 2 at 80KB). Four independent
//   __syncthreads domains per CU with half-length load/store bursts keep
//   the memory pipe continuously fed; VALU (~20%) and LDS (~20%) hide.
//   Phase A: W-mix in-register -> Ysh (10 ds_write_b128)
//   Phase B: accumulate R^T·Y into resident x4[] (identity already there),
//            store contiguous. One barrier total, ~65 VGPR, no spill.

#define IMG   2000
#define BSZ   10
#define TC    200                 // chunk size = 2000/10
#define CHW   (IMG * IMG)         // 4,000,000
#define NW4   (TC / 4)            // 50 float4 slots per full chunk-row slice
#define NW4H  25                  // half-line: 25 float4 per chunk-row slice

__global__ __launch_bounds__(256, 4)
void reset_half(const float* __restrict__ x,
                const float* __restrict__ leftm,
                const float* __restrict__ rightm,
                float* __restrict__ out)
{
    // Y[ih][jw][wo4] : 10*10*25 float4 = 40,000 B -> 4 blocks/CU
    __shared__ __align__(16) float4 Ysh[BSZ * BSZ * NW4H];

    const int t    = threadIdx.x;
    const int bid  = blockIdx.x;       // 0..6399
    const int line = bid >> 1;         // (b,h) line id, consecutive bids share
    const int half = bid & 1;          //   a line -> L2-adjacent streams
    const int b    = line / TC;
    const int h    = line - b * TC;

    const int  ih     = t / NW4H;      // 0..9 (valid for t < 250)
    const int  wo4    = t - ih * NW4H; // 0..24
    const bool active = (t < BSZ * NW4H);
    const int  colb   = half * NW4H;   // float4 offset inside each 50-slot chunk

    // R^T row for this thread's output row jh == ih: r[ihp] = R[ihp][ih].
    // Tiny, L1-resident, issued before the main burst.
    float r[BSZ];
    {
        const int jh = active ? ih : 0;
        #pragma unroll
        for (int ihp = 0; ihp < BSZ; ++ihp)
            r[ihp] = rightm[ihp * BSZ + jh];
    }

    // ---- load X row-slice: 10 float4s, 2-3 contiguous 400B segments/wave-inst
    float4 x4[BSZ];
    if (active) {
        const float4* rowp =
            (const float4*)(x + (size_t)b * CHW + (size_t)(ih * TC + h) * IMG);
        #pragma unroll
        for (int iw = 0; iw < BSZ; ++iw)
            x4[iw] = rowp[iw * NW4 + colb + wo4];

        // ---- phase A: Y[ih][jw][wo4] = sum_iw L[jw][iw] * x4[iw]
        // L indices compile-time + uniform -> s_load (SGPR broadcast).
        #pragma unroll
        for (int jw = 0; jw < BSZ; ++jw) {
            const float l0 = leftm[jw * BSZ + 0];
            float4 y;
            y.x = l0 * x4[0].x; y.y = l0 * x4[0].y;
            y.z = l0 * x4[0].z; y.w = l0 * x4[0].w;
            #pragma unroll
            for (int iw = 1; iw < BSZ; ++iw) {
                const float l = leftm[jw * BSZ + iw];
                y.x += l * x4[iw].x; y.y += l * x4[iw].y;
                y.z += l * x4[iw].z; y.w += l * x4[iw].w;
            }
            Ysh[(ih * BSZ + jw) * NW4H + wo4] = y;
        }
    }

    __syncthreads();

    // ---- phase B: x4[jw] += sum_ihp r[ihp] * Y[ihp][jw][wo4]
    // (x4 holds the identity term; becomes the final output.)
    // Reads: 3 lane-groups per inst -> same-address broadcast + contiguous
    // 400B segments; no serializing conflicts.
    if (active) {
        #pragma unroll
        for (int ihp = 0; ihp < BSZ; ++ihp) {
            const float rr = r[ihp];
            #pragma unroll
            for (int jw = 0; jw < BSZ; ++jw) {
                const float4 y = Ysh[(ihp * BSZ + jw) * NW4H + wo4];
                x4[jw].x += rr * y.x; x4[jw].y += rr * y.y;
                x4[jw].z += rr * y.z; x4[jw].w += rr * y.w;
            }
        }
        // ---- store: same 400B-segment pattern as the loads
        float4* orow =
            (float4*)(out + (size_t)b * CHW + (size_t)(ih * TC + h) * IMG);
        #pragma unroll
        for (int jw = 0; jw < BSZ; ++jw)
            orow[jw * NW4 + colb + wo4] = x4[jw];
    }
}

extern "C" void kernel_launch(void* const* d_in, const int* in_sizes, int n_in,
                              void* d_out, int out_size, void* d_ws, size_t ws_size,
                              hipStream_t stream) {
    const float* x = (const float*)d_in[0];
    const float* L = (const float*)d_in[1];
    const float* R = (const float*)d_in[2];
    float* out = (float*)d_out;
    // one block per (b, h, half): 16 * 200 * 2 = 6400 blocks, 256 threads
    reset_half<<<6400, 256, 0, stream>>>(x, L, R, out);
}